// Round 6
// baseline (141.150 us; speedup 1.0000x reference)
//
#include <hip/hip_runtime.h>
#include <hip/hip_bf16.h>
#include <math.h>

// Problem constants (fixed by setup_inputs)
#define BATCH 8
#define SEQ   4096
#define DIM   512        // D
#define FDIM  4          // F
#define M_TOTAL (BATCH*SEQ)   // 32768 positions
#define K_TOTAL (2*DIM)       // 1024 (cat = [ctx; q])
#define N_TOTAL DIM           // 512

#define PRE_BLOCKS (M_TOTAL/4)          // 8192 blocks, 4 positions (waves) each
#define WCONV_BLOCKS ((K_TOTAL/64)*(N_TOTAL/64))  // 16*8 = 128 tiles

// GEMM tile geometry: 128x128, BK=64, 4 waves (2x2), m97 structure
#define BM 128
#define BN 128
#define BK 64
#define NKT (K_TOTAL/BK)    // 16 K-tiles
#define GEMM_BLOCKS ((M_TOTAL/BM)*(N_TOTAL/BN))   // 256*4 = 1024

typedef __bf16 bf16x8 __attribute__((ext_vector_type(8)));
typedef float  f32x4  __attribute__((ext_vector_type(4)));

__device__ __forceinline__ void gload_lds16(const void* g, void* l) {
    __builtin_amdgcn_global_load_lds(
        (__attribute__((address_space(1))) void*)(void*)g,
        (__attribute__((address_space(3))) void*)l,
        16, 0, 0);
}

__device__ __forceinline__ float dot4(float4 a, float4 b) {
    return a.x*b.x + a.y*b.y + a.z*b.z + a.w*b.w;
}

__device__ __forceinline__ void store_bf4(__hip_bfloat16* dst, float4 v) {
    __hip_bfloat16 t[4];
    t[0] = __float2bfloat16(v.x); t[1] = __float2bfloat16(v.y);
    t[2] = __float2bfloat16(v.z); t[3] = __float2bfloat16(v.w);
    *reinterpret_cast<uint2*>(dst) = *reinterpret_cast<const uint2*>(t);
}

__device__ __forceinline__ float fast_tanh(float x) {
    // tanh(x) = 1 - 2/(e^{2x}+1); saturates correctly for |x| large
    float e = __expf(2.f * x);
    return 1.f - 2.f * __builtin_amdgcn_rcpf(e + 1.f);
}

// ---------------------------------------------------------------------------
// Kernel 1 (fused): blocks [0, PRE_BLOCKS): wave-per-position attention
//                   blocks [PRE_BLOCKS, +WCONV_BLOCKS): W_out transpose->bf16
// Writes full cat = [ctx; q] bf16 [M,1024] and gate f32 [M].
// ---------------------------------------------------------------------------
__global__ __launch_bounds__(256)
void pre_kernel(const float* __restrict__ inputs,
                const float* __restrict__ values,
                const float* __restrict__ W,
                const float* __restrict__ w_score,
                const float* __restrict__ b_score,
                const int*   __restrict__ n_ptr,
                __hip_bfloat16* __restrict__ cat,
                float* __restrict__ gate,
                __hip_bfloat16* __restrict__ Wt)
{
    __shared__ float ws[64][65];   // only used by the wconv path (16.6 KB)

    const int tid  = threadIdx.x;

    if (blockIdx.x >= PRE_BLOCKS) {
        // ---- W_out [1024,512] f32 -> Wt [512,1024] bf16, 64x64 LDS tile ----
        const int t  = blockIdx.x - PRE_BLOCKS;
        const int k0 = (t & 15) * 64;     // row tile in W (K dim)
        const int n0 = (t >> 4) * 64;     // col tile in W (N dim)
        #pragma unroll
        for (int i = 0; i < 16; ++i) {
            int e = i * 256 + tid;
            int r = e >> 6, c = e & 63;
            ws[r][c] = W[(size_t)(k0 + r) * N_TOTAL + n0 + c];
        }
        __syncthreads();
        #pragma unroll
        for (int i = 0; i < 16; ++i) {
            int e = i * 256 + tid;
            int nr = e >> 6, kc = e & 63;
            Wt[(size_t)(n0 + nr) * K_TOTAL + k0 + kc] = __float2bfloat16(ws[kc][nr]);
        }
        return;
    }

    // ---- wave-per-position attention: no LDS, no barriers ----
    const int lane = tid & 63;
    const int wv   = tid >> 6;
    const int p    = blockIdx.x * 4 + wv;

    const float4* qg = (const float4*)(inputs + (size_t)p * DIM);
    float4 qa = qg[lane], qb = qg[lane + 64];

    const float4* vg = (const float4*)(values + (size_t)p * (FDIM*DIM));
    float4 ma[4], mb[4];
    float s[4];
    #pragma unroll
    for (int f = 0; f < 4; ++f) {
        ma[f] = vg[f * 128 + lane];
        mb[f] = vg[f * 128 + lane + 64];
        s[f] = dot4(qa, ma[f]) + dot4(qb, mb[f]);
    }
    const float4* wg = (const float4*)w_score;
    float g = dot4(qa, wg[lane]) + dot4(qb, wg[lane + 64]);

    // butterfly reduce the 4 scores + gate across the wave
    #pragma unroll
    for (int off = 1; off < 64; off <<= 1) {
        s[0] += __shfl_xor(s[0], off, 64);
        s[1] += __shfl_xor(s[1], off, 64);
        s[2] += __shfl_xor(s[2], off, 64);
        s[3] += __shfl_xor(s[3], off, 64);
        g    += __shfl_xor(g,    off, 64);
    }

    const int nv = *n_ptr;
    #pragma unroll
    for (int f = 0; f < 4; ++f) if (f >= nv) s[f] = -1e9f;
    float mx = fmaxf(fmaxf(s[0], s[1]), fmaxf(s[2], s[3]));
    float e0 = __expf(s[0] - mx), e1 = __expf(s[1] - mx);
    float e2 = __expf(s[2] - mx), e3 = __expf(s[3] - mx);
    float inv = __builtin_amdgcn_rcpf(e0 + e1 + e2 + e3);
    float a[4] = { e0 * inv, e1 * inv, e2 * inv, e3 * inv };

    float4 ca = {0.f, 0.f, 0.f, 0.f}, cb = {0.f, 0.f, 0.f, 0.f};
    #pragma unroll
    for (int f = 0; f < 4; ++f) {
        ca.x += a[f] * ma[f].x; ca.y += a[f] * ma[f].y;
        ca.z += a[f] * ma[f].z; ca.w += a[f] * ma[f].w;
        cb.x += a[f] * mb[f].x; cb.y += a[f] * mb[f].y;
        cb.z += a[f] * mb[f].z; cb.w += a[f] * mb[f].w;
    }

    __hip_bfloat16* cp = cat + (size_t)p * K_TOTAL;
    store_bf4(cp +        4 * lane, ca);
    store_bf4(cp + 256  + 4 * lane, cb);
    store_bf4(cp + 512  + 4 * lane, qa);
    store_bf4(cp + 768  + 4 * lane, qb);

    if (lane == 0) {
        float t = g + b_score[0];
        gate[p] = __builtin_amdgcn_rcpf(1.f + __expf(-t));
    }
}

// ---------------------------------------------------------------------------
// Kernel 2: out = tanh(cat @ W_out) * gate + q   (q = bf16 residual from cat)
// m97 structure: 128x128 tile, BK=64, 4 waves (2x2), 4x4 frags/wave,
// single-buffer 2-barrier K-loop, global_load_lds width-16 both operands,
// XOR source-swizzle (== read swizzle) for conflict-free ds_read_b128.
// __launch_bounds__(256,4): <=128 VGPR -> 4 blocks/CU -> grid 1024 = one round.
// Bijective XCD-chunked block swizzle groups the 4 bn-blocks of each bm on
// one XCD for A-panel L2 reuse.
// ---------------------------------------------------------------------------
__global__ __launch_bounds__(256, 4)
void gemm_ep(const __hip_bfloat16* __restrict__ A,   // cat [M,1024]
             const __hip_bfloat16* __restrict__ Bt,  // Wt  [512,1024]
             const float* __restrict__ gate,
             float* __restrict__ out)
{
    __shared__ __align__(16) __hip_bfloat16 As[BM * BK];  // 16 KB
    __shared__ __align__(16) __hip_bfloat16 Bs[BN * BK];  // 16 KB
    __shared__ float gateLds[BM];

    const int tid = threadIdx.x;
    // XCD-chunked bijective swizzle (nwg=1024, 8 XCDs -> 128 logicals each).
    // Hardware round-robins dispatch id -> XCD, so ids with id%8==x form
    // XCD x's stream; give that stream consecutive logical tiles.
    const int logical = (blockIdx.x & 7) * (GEMM_BLOCKS / 8) + (blockIdx.x >> 3);
    const int bm = logical >> 2;     // 0..255 (4 consecutive logicals share bm)
    const int bn = logical & 3;      // 0..3

    const int wid  = tid >> 6;
    const int lane = tid & 63;
    const int wr   = wid >> 1;       // wave row 0..1
    const int wc   = wid & 1;        // wave col 0..1
    const int la   = lane & 15;
    const int lb   = lane >> 4;

    const __hip_bfloat16* Ag = A  + (size_t)(bm * BM) * K_TOTAL;
    const __hip_bfloat16* Bg = Bt + (size_t)(bn * BN) * K_TOTAL;

    if (tid < BM) gateLds[tid] = gate[bm * BM + tid];

    f32x4 acc[4][4] = {};

    for (int kt = 0; kt < K_TOTAL; kt += BK) {
        __syncthreads();   // protect LDS from previous iteration's readers
        // stage 128x64 of A and B: 4 passes x 256 threads x 16B each.
        // LDS dest linear (global_load_lds requirement); the GLOBAL source
        // chunk index carries the XOR swizzle, matching the ds_read XOR.
        #pragma unroll
        for (int ps = 0; ps < 4; ++ps) {
            int cl  = ps * 256 + tid;        // linear 16B-chunk index 0..1023
            int row = cl >> 3;               // 8 chunks per 64-elem row
            int c   = cl & 7;
            int sc_ = c ^ (row & 7);
            gload_lds16(Ag + (size_t)row * K_TOTAL + kt + sc_ * 8, As + cl * 8);
            gload_lds16(Bg + (size_t)row * K_TOTAL + kt + sc_ * 8, Bs + cl * 8);
        }
        __syncthreads();   // compiler drains vmcnt(0) before this barrier

        #pragma unroll
        for (int kk = 0; kk < 2; ++kk) {
            bf16x8 af[4], bfv[4];
            #pragma unroll
            for (int i = 0; i < 4; ++i) {
                int row = wr * 64 + i * 16 + la;
                int cc  = (kk * 4 + lb) ^ (row & 7);
                af[i] = *reinterpret_cast<const bf16x8*>(As + row * BK + cc * 8);
            }
            #pragma unroll
            for (int j = 0; j < 4; ++j) {
                int row = wc * 64 + j * 16 + la;
                int cc  = (kk * 4 + lb) ^ (row & 7);
                bfv[j] = *reinterpret_cast<const bf16x8*>(Bs + row * BK + cc * 8);
            }
            #pragma unroll
            for (int i = 0; i < 4; ++i)
                #pragma unroll
                for (int j = 0; j < 4; ++j)
                    acc[i][j] = __builtin_amdgcn_mfma_f32_16x16x32_bf16(af[i], bfv[j], acc[i][j], 0, 0, 0);
        }
    }

    // Epilogue: C/D mapping col = lane&15, row = (lane>>4)*4 + reg  [m89/m91]
    const int row0 = bm * BM + wr * 64;
    const int col0 = bn * BN + wc * 64;
    #pragma unroll
    for (int i = 0; i < 4; ++i) {
        #pragma unroll
        for (int j = 0; j < 4; ++j) {
            const int col = col0 + j * 16 + la;
            const int rb  = row0 + i * 16 + lb * 4;
            #pragma unroll
            for (int r = 0; r < 4; ++r) {
                const int row = rb + r;
                // residual from the bf16 q-half of cat (rows L2-hot from staging)
                float q = __bfloat162float(A[(size_t)row * K_TOTAL + 512 + col]);
                float v = fast_tanh(acc[i][j][r]) * gateLds[row - bm * BM] + q;
                out[(size_t)row * DIM + col] = v;
            }
        }
    }
}

// ---------------------------------------------------------------------------
extern "C" void kernel_launch(void* const* d_in, const int* in_sizes, int n_in,
                              void* d_out, int out_size, void* d_ws, size_t ws_size,
                              hipStream_t stream) {
    const float* inputs  = (const float*)d_in[0];
    const float* values  = (const float*)d_in[1];
    const float* W_out   = (const float*)d_in[2];
    const float* w_score = (const float*)d_in[3];
    const float* b_score = (const float*)d_in[4];
    const int*   n_ptr   = (const int*)d_in[5];
    float* out = (float*)d_out;

    char* ws = (char*)d_ws;
    __hip_bfloat16* cat  = (__hip_bfloat16*)ws;                                   // 64 MiB
    float*          gate = (float*)(ws + (size_t)M_TOTAL * K_TOTAL * 2);          // 128 KiB
    __hip_bfloat16* Wt   = (__hip_bfloat16*)(ws + (size_t)M_TOTAL * K_TOTAL * 2
                                                + (size_t)M_TOTAL * 4);           // 1 MiB

    pre_kernel<<<PRE_BLOCKS + WCONV_BLOCKS, 256, 0, stream>>>(
        inputs, values, W_out, w_score, b_score, n_ptr, cat, gate, Wt);
    gemm_ep<<<GEMM_BLOCKS, 256, 0, stream>>>(cat, Wt, gate, out);
}

// Round 7
// 131.506 us; speedup vs baseline: 1.0733x; 1.0733x over previous
//
#include <hip/hip_runtime.h>
#include <hip/hip_bf16.h>
#include <math.h>

// Problem constants (fixed by setup_inputs)
#define BATCH 8
#define SEQ   4096
#define DIM   512        // D
#define FDIM  4          // F
#define M_TOTAL (BATCH*SEQ)   // 32768 positions
#define K_TOTAL (2*DIM)       // 1024 (cat = [ctx; q])
#define N_TOTAL DIM           // 512

#define PRE_BLOCKS (M_TOTAL/4)          // 8192 blocks, 4 positions (waves) each
#define WCONV_BLOCKS ((K_TOTAL/64)*(N_TOTAL/64))  // 16*8 = 128 tiles

// GEMM tile geometry: 128x128, BK=64, 4 waves (2x2), m97 structure
#define BM 128
#define BN 128
#define BK 64
#define NKT (K_TOTAL/BK)    // 16 K-tiles
#define GEMM_BLOCKS ((M_TOTAL/BM)*(N_TOTAL/BN))   // 256*4 = 1024

typedef __bf16 bf16x8 __attribute__((ext_vector_type(8)));
typedef float  f32x4  __attribute__((ext_vector_type(4)));

__device__ __forceinline__ void gload_lds16(const void* g, void* l) {
    __builtin_amdgcn_global_load_lds(
        (__attribute__((address_space(1))) void*)(void*)g,
        (__attribute__((address_space(3))) void*)l,
        16, 0, 0);
}

__device__ __forceinline__ float dot4(float4 a, float4 b) {
    return a.x*b.x + a.y*b.y + a.z*b.z + a.w*b.w;
}

__device__ __forceinline__ void store_bf4(__hip_bfloat16* dst, float4 v) {
    __hip_bfloat16 t[4];
    t[0] = __float2bfloat16(v.x); t[1] = __float2bfloat16(v.y);
    t[2] = __float2bfloat16(v.z); t[3] = __float2bfloat16(v.w);
    *reinterpret_cast<uint2*>(dst) = *reinterpret_cast<const uint2*>(t);
}

__device__ __forceinline__ float fast_tanh(float x) {
    // tanh(x) = 1 - 2/(e^{2x}+1); saturates correctly for |x| large
    float e = __expf(2.f * x);
    return 1.f - 2.f * __builtin_amdgcn_rcpf(e + 1.f);
}

// ---------------------------------------------------------------------------
// Kernel 1 (fused): blocks [0, PRE_BLOCKS): wave-per-position attention
//                   blocks [PRE_BLOCKS, +WCONV_BLOCKS): W_out transpose->bf16
// Writes full cat = [ctx; q] bf16 [M,1024] and gate f32 [M].
// ---------------------------------------------------------------------------
__global__ __launch_bounds__(256)
void pre_kernel(const float* __restrict__ inputs,
                const float* __restrict__ values,
                const float* __restrict__ W,
                const float* __restrict__ w_score,
                const float* __restrict__ b_score,
                const int*   __restrict__ n_ptr,
                __hip_bfloat16* __restrict__ cat,
                float* __restrict__ gate,
                __hip_bfloat16* __restrict__ Wt)
{
    __shared__ float ws[64][65];   // only used by the wconv path (16.6 KB)

    const int tid  = threadIdx.x;

    if (blockIdx.x >= PRE_BLOCKS) {
        // ---- W_out [1024,512] f32 -> Wt [512,1024] bf16, 64x64 LDS tile ----
        const int t  = blockIdx.x - PRE_BLOCKS;
        const int k0 = (t & 15) * 64;     // row tile in W (K dim)
        const int n0 = (t >> 4) * 64;     // col tile in W (N dim)
        #pragma unroll
        for (int i = 0; i < 16; ++i) {
            int e = i * 256 + tid;
            int r = e >> 6, c = e & 63;
            ws[r][c] = W[(size_t)(k0 + r) * N_TOTAL + n0 + c];
        }
        __syncthreads();
        #pragma unroll
        for (int i = 0; i < 16; ++i) {
            int e = i * 256 + tid;
            int nr = e >> 6, kc = e & 63;
            Wt[(size_t)(n0 + nr) * K_TOTAL + k0 + kc] = __float2bfloat16(ws[kc][nr]);
        }
        return;
    }

    // ---- wave-per-position attention: no LDS, no barriers ----
    const int lane = tid & 63;
    const int wv   = tid >> 6;
    const int p    = blockIdx.x * 4 + wv;

    const float4* qg = (const float4*)(inputs + (size_t)p * DIM);
    float4 qa = qg[lane], qb = qg[lane + 64];

    const float4* vg = (const float4*)(values + (size_t)p * (FDIM*DIM));
    float4 ma[4], mb[4];
    float s[4];
    #pragma unroll
    for (int f = 0; f < 4; ++f) {
        ma[f] = vg[f * 128 + lane];
        mb[f] = vg[f * 128 + lane + 64];
        s[f] = dot4(qa, ma[f]) + dot4(qb, mb[f]);
    }
    const float4* wg = (const float4*)w_score;
    float g = dot4(qa, wg[lane]) + dot4(qb, wg[lane + 64]);

    // butterfly reduce the 4 scores + gate across the wave
    #pragma unroll
    for (int off = 1; off < 64; off <<= 1) {
        s[0] += __shfl_xor(s[0], off, 64);
        s[1] += __shfl_xor(s[1], off, 64);
        s[2] += __shfl_xor(s[2], off, 64);
        s[3] += __shfl_xor(s[3], off, 64);
        g    += __shfl_xor(g,    off, 64);
    }

    const int nv = *n_ptr;
    #pragma unroll
    for (int f = 0; f < 4; ++f) if (f >= nv) s[f] = -1e9f;
    float mx = fmaxf(fmaxf(s[0], s[1]), fmaxf(s[2], s[3]));
    float e0 = __expf(s[0] - mx), e1 = __expf(s[1] - mx);
    float e2 = __expf(s[2] - mx), e3 = __expf(s[3] - mx);
    float inv = __builtin_amdgcn_rcpf(e0 + e1 + e2 + e3);
    float a[4] = { e0 * inv, e1 * inv, e2 * inv, e3 * inv };

    float4 ca = {0.f, 0.f, 0.f, 0.f}, cb = {0.f, 0.f, 0.f, 0.f};
    #pragma unroll
    for (int f = 0; f < 4; ++f) {
        ca.x += a[f] * ma[f].x; ca.y += a[f] * ma[f].y;
        ca.z += a[f] * ma[f].z; ca.w += a[f] * ma[f].w;
        cb.x += a[f] * mb[f].x; cb.y += a[f] * mb[f].y;
        cb.z += a[f] * mb[f].z; cb.w += a[f] * mb[f].w;
    }

    __hip_bfloat16* cp = cat + (size_t)p * K_TOTAL;
    store_bf4(cp +        4 * lane, ca);
    store_bf4(cp + 256  + 4 * lane, cb);
    store_bf4(cp + 512  + 4 * lane, qa);
    store_bf4(cp + 768  + 4 * lane, qb);

    if (lane == 0) {
        float t = g + b_score[0];
        gate[p] = __builtin_amdgcn_rcpf(1.f + __expf(-t));
    }
}

// ---------------------------------------------------------------------------
// Kernel 2: out = tanh(cat @ W_out) * gate + q   (q = bf16 residual from cat)
// m97 structure: 128x128 tile, BK=64, 4 waves (2x2), 4x4 frags/wave,
// single-buffer 2-barrier K-loop, global_load_lds width-16 both operands,
// XOR source-swizzle (== read swizzle) for conflict-free ds_read_b128.
// __launch_bounds__(256,4): <=128 VGPR -> 4 blocks/CU -> grid 1024 = one round.
// NATURAL block order (R7: XCD swizzle removed — 4 consecutive blocks share
// one A-panel and dispatch adjacently; A is 64 MiB, fully L3-resident).
// ---------------------------------------------------------------------------
__global__ __launch_bounds__(256, 4)
void gemm_ep(const __hip_bfloat16* __restrict__ A,   // cat [M,1024]
             const __hip_bfloat16* __restrict__ Bt,  // Wt  [512,1024]
             const float* __restrict__ gate,
             float* __restrict__ out)
{
    __shared__ __align__(16) __hip_bfloat16 As[BM * BK];  // 16 KB
    __shared__ __align__(16) __hip_bfloat16 Bs[BN * BK];  // 16 KB
    __shared__ float gateLds[BM];

    const int tid = threadIdx.x;
    const int bm = blockIdx.x >> 2;     // 0..255 (4 consecutive blocks share bm)
    const int bn = blockIdx.x & 3;      // 0..3

    const int wid  = tid >> 6;
    const int lane = tid & 63;
    const int wr   = wid >> 1;       // wave row 0..1
    const int wc   = wid & 1;        // wave col 0..1
    const int la   = lane & 15;
    const int lb   = lane >> 4;

    const __hip_bfloat16* Ag = A  + (size_t)(bm * BM) * K_TOTAL;
    const __hip_bfloat16* Bg = Bt + (size_t)(bn * BN) * K_TOTAL;

    if (tid < BM) gateLds[tid] = gate[bm * BM + tid];

    f32x4 acc[4][4] = {};

    for (int kt = 0; kt < K_TOTAL; kt += BK) {
        __syncthreads();   // protect LDS from previous iteration's readers
        // stage 128x64 of A and B: 4 passes x 256 threads x 16B each.
        // LDS dest linear (global_load_lds requirement); the GLOBAL source
        // chunk index carries the XOR swizzle, matching the ds_read XOR.
        #pragma unroll
        for (int ps = 0; ps < 4; ++ps) {
            int cl  = ps * 256 + tid;        // linear 16B-chunk index 0..1023
            int row = cl >> 3;               // 8 chunks per 64-elem row
            int c   = cl & 7;
            int sc_ = c ^ (row & 7);
            gload_lds16(Ag + (size_t)row * K_TOTAL + kt + sc_ * 8, As + cl * 8);
            gload_lds16(Bg + (size_t)row * K_TOTAL + kt + sc_ * 8, Bs + cl * 8);
        }
        __syncthreads();   // compiler drains vmcnt(0) before this barrier

        #pragma unroll
        for (int kk = 0; kk < 2; ++kk) {
            bf16x8 af[4], bfv[4];
            #pragma unroll
            for (int i = 0; i < 4; ++i) {
                int row = wr * 64 + i * 16 + la;
                int cc  = (kk * 4 + lb) ^ (row & 7);
                af[i] = *reinterpret_cast<const bf16x8*>(As + row * BK + cc * 8);
            }
            #pragma unroll
            for (int j = 0; j < 4; ++j) {
                int row = wc * 64 + j * 16 + la;
                int cc  = (kk * 4 + lb) ^ (row & 7);
                bfv[j] = *reinterpret_cast<const bf16x8*>(Bs + row * BK + cc * 8);
            }
            #pragma unroll
            for (int i = 0; i < 4; ++i)
                #pragma unroll
                for (int j = 0; j < 4; ++j)
                    acc[i][j] = __builtin_amdgcn_mfma_f32_16x16x32_bf16(af[i], bfv[j], acc[i][j], 0, 0, 0);
        }
    }

    // Epilogue: C/D mapping col = lane&15, row = (lane>>4)*4 + reg  [m89/m91]
    const int row0 = bm * BM + wr * 64;
    const int col0 = bn * BN + wc * 64;
    #pragma unroll
    for (int i = 0; i < 4; ++i) {
        #pragma unroll
        for (int j = 0; j < 4; ++j) {
            const int col = col0 + j * 16 + la;
            const int rb  = row0 + i * 16 + lb * 4;
            #pragma unroll
            for (int r = 0; r < 4; ++r) {
                const int row = rb + r;
                // residual from the bf16 q-half of cat (rows L2-hot from staging)
                float q = __bfloat162float(A[(size_t)row * K_TOTAL + 512 + col]);
                float v = fast_tanh(acc[i][j][r]) * gateLds[row - bm * BM] + q;
                out[(size_t)row * DIM + col] = v;
            }
        }
    }
}

// ---------------------------------------------------------------------------
extern "C" void kernel_launch(void* const* d_in, const int* in_sizes, int n_in,
                              void* d_out, int out_size, void* d_ws, size_t ws_size,
                              hipStream_t stream) {
    const float* inputs  = (const float*)d_in[0];
    const float* values  = (const float*)d_in[1];
    const float* W_out   = (const float*)d_in[2];
    const float* w_score = (const float*)d_in[3];
    const float* b_score = (const float*)d_in[4];
    const int*   n_ptr   = (const int*)d_in[5];
    float* out = (float*)d_out;

    char* ws = (char*)d_ws;
    __hip_bfloat16* cat  = (__hip_bfloat16*)ws;                                   // 64 MiB
    float*          gate = (float*)(ws + (size_t)M_TOTAL * K_TOTAL * 2);          // 128 KiB
    __hip_bfloat16* Wt   = (__hip_bfloat16*)(ws + (size_t)M_TOTAL * K_TOTAL * 2
                                                + (size_t)M_TOTAL * 4);           // 1 MiB

    pre_kernel<<<PRE_BLOCKS + WCONV_BLOCKS, 256, 0, stream>>>(
        inputs, values, W_out, w_score, b_score, n_ptr, cat, gate, Wt);
    gemm_ep<<<GEMM_BLOCKS, 256, 0, stream>>>(cat, Wt, gate, out);
}